// Round 7
// baseline (131.168 us; speedup 1.0000x reference)
//
#include <hip/hip_runtime.h>
#include <math.h>

#define BB 8
#define HH 256
#define KK 256
#define EE 128
#define E4 (EE / 4)          // 32 float4 chunks per row
#define NBIN 1024            // 1000 bins padded
#define NBH (BB * HH)        // 2048

// DPP-based add: x + dpp_mov(x).
template <int CTRL, int RM>
__device__ __forceinline__ float dpp_add(float x) {
    int d = __builtin_amdgcn_update_dpp(0, __float_as_int(x), CTRL, RM, 0xf, true);
    return x + __int_as_float(d);
}
__device__ __forceinline__ float dpp_reduce_wave(float x) {
    x = dpp_add<0x111, 0xf>(x);  // row_shr:1
    x = dpp_add<0x112, 0xf>(x);  // row_shr:2
    x = dpp_add<0x114, 0xf>(x);  // row_shr:4
    x = dpp_add<0x118, 0xf>(x);  // row_shr:8
    x = dpp_add<0x142, 0xa>(x);  // row_bcast:15 -> lanes 31,63 have 32-sums
    x = dpp_add<0x143, 0xc>(x);  // row_bcast:31 -> lane 63 has 64-sum
    return x;
}

// ---------------- K0: gather+transpose key rows; zero accumulators. ----------------
// KgT[b][e4][k] (float4) = key_emb[key_seq[b,k]][4*e4 .. 4*e4+3]
__global__ __launch_bounds__(256) void kvmn_gather(
    const float* __restrict__ key_emb,   // [VOCAB,E]
    const int*   __restrict__ key_seq,   // [B,K]
    float4* __restrict__ KgT,            // [B,E4,K]
    float*  __restrict__ sum_ws,         // [B,E] zeroed here
    int*    __restrict__ c_ws)           // [B]   zeroed here
{
    const int g  = blockIdx.x * 256 + threadIdx.x;  // 65536 threads
    const int b  = g >> 13;
    const int e4 = (g >> 8) & 31;
    const int k  = g & 255;
    const int row = key_seq[b * KK + k];
    const float4 v = *(const float4*)&key_emb[(size_t)row * EE + e4 * 4];
    KgT[((size_t)b * E4 + e4) * KK + k] = v;   // k-consecutive: coalesced store
    if (g < BB * EE) sum_ws[g] = 0.0f;
    if (g < BB)      c_ws[g]   = 0;
}

// ---------------- K1: one block per (b,h). Dense phase-1, hist scatter. ----------------
__global__ __launch_bounds__(256) void kvmn_attn(
    const float*  __restrict__ hidden,    // [B,H,E]
    const float4* __restrict__ KgT,       // [B,E4,K]
    const int*    __restrict__ value_seq, // [B,H,K]
    const int*    __restrict__ mask,      // [B,H,K]
    float* __restrict__ part_hist,        // [NBH, NBIN]
    int*   __restrict__ c_ws)             // [B]
{
    __shared__ float4 sh_h[E4];
    __shared__ float  hist[NBIN];
    __shared__ float  fslot[4];
    __shared__ int    islot[4];

    const int bid  = blockIdx.x;
    const int b    = bid >> 8;
    const int h    = bid & 255;
    const int tid  = threadIdx.x;        // == k
    const int w    = tid >> 6;
    const int lane = tid & 63;

    if (tid < E4)
        sh_h[tid] = *(const float4*)&hidden[((size_t)b * HH + h) * EE + tid * 4];
    *(float4*)&hist[tid * 4] = make_float4(0.f, 0.f, 0.f, 0.f);

    const size_t idx = ((size_t)b * HH + h) * KK + tid;
    const int m  = mask[idx];
    const int vs = value_seq[idx];
    __syncthreads();

    // ---- phase 1 (dense, affine): u[k] = sum_e4 dot(KgT[b][e4][k], h[e4]) / sqrt(E)
    const float4* kcol = KgT + (size_t)b * E4 * KK + tid;
    float acc = 0.0f;
    #pragma unroll 8
    for (int e4 = 0; e4 < E4; ++e4) {
        const float4 kv = kcol[(size_t)e4 * KK];   // coalesced: lanes k-consecutive
        const float4 hv = sh_h[e4];                // LDS broadcast
        acc += kv.x * hv.x + kv.y * hv.y + kv.z * hv.z + kv.w * hv.w;
    }

    // ---- phase 2: d = exp(u)*mask; block denom; p
    const float d = expf(acc * 0.08838834764831845f) * (float)m;
    const float s = dpp_reduce_wave(d);
    if (lane == 63) fslot[w] = s;
    const unsigned long long bal = __ballot(m != 0 && vs != 0);
    if (lane == 0) islot[w] = (bal != 0ull) ? 1 : 0;
    __syncthreads();
    const float denom = fslot[0] + fslot[1] + fslot[2] + fslot[3];
    const float p = d * (1.0f / (denom + 1e-10f));

    // ---- hist scatter (p==0 contributes nothing; bin 0 has zero value row)
    atomicAdd(&hist[vs], p);
    if (tid == 0) {
        const int f = islot[0] | islot[1] | islot[2] | islot[3];
        if (f) atomicAdd(&c_ws[b], 1);   // o[b,h,:] nonzero -> counts for every e
    }
    __syncthreads();

    *(float4*)&part_hist[(size_t)bid * NBIN + tid * 4] = *(float4*)&hist[tid * 4];
}

// ---------------- K2: 64 blocks = (b, 8 bin-chunks). Reduce hists + chunk-GEMM. ----------------
__global__ __launch_bounds__(256) void kvmn_hreduce(
    const float* __restrict__ part_hist,  // [NBH, NBIN]
    const float* __restrict__ value_emb,  // [FVOCAB, E]
    float* __restrict__ sum_ws)           // [B, E]
{
    __shared__ float Hsh[2][128];
    __shared__ float gs[2][128];

    const int bid  = blockIdx.x;          // 64
    const int b    = bid >> 3;
    const int c    = bid & 7;             // bin chunk: [c*128, c*128+128)
    const int t    = threadIdx.x;
    const int binl = t & 127;
    const int hh   = t >> 7;              // h half: 0/1

    // reduce this 128-bin slice over 128 h's (each thread one bin, half the h's)
    float s = 0.0f;
    const float* base = part_hist + ((size_t)(b * HH) + hh * 128) * NBIN + c * 128 + binl;
    #pragma unroll 8
    for (int i = 0; i < 128; ++i)
        s += base[(size_t)i * NBIN];
    Hsh[hh][binl] = s;
    __syncthreads();
    if (t < 128) Hsh[0][t] = Hsh[0][t] + Hsh[1][t];
    __syncthreads();

    // chunk GEMM: partial_out[e] = sum_{bin in chunk} H[bin] * V[bin, e]
    const int e  = binl;
    const int rr = hh;                    // split 128 bins into 2x64
    float acc = 0.0f;
    #pragma unroll 8
    for (int j = 0; j < 64; ++j) {
        const int gb = c * 128 + rr * 64 + j;
        if (gb < 1000)
            acc += Hsh[0][rr * 64 + j] * value_emb[(size_t)gb * EE + e];
    }
    gs[rr][e] = acc;
    __syncthreads();
    if (t < 128)
        atomicAdd(&sum_ws[b * EE + t], gs[0][t] + gs[1][t]);
}

// ---------------- K3: divide by valid-h count. ----------------
__global__ __launch_bounds__(128) void kvmn_div(
    const float* __restrict__ sum_ws,
    const int*   __restrict__ c_ws,
    float* __restrict__ out)
{
    const int b = blockIdx.x;
    const int t = threadIdx.x;
    out[b * EE + t] = sum_ws[b * EE + t] / (float)c_ws[b];
}

extern "C" void kernel_launch(void* const* d_in, const int* in_sizes, int n_in,
                              void* d_out, int out_size, void* d_ws, size_t ws_size,
                              hipStream_t stream) {
    const float* hidden    = (const float*)d_in[0];
    const float* key_emb   = (const float*)d_in[1];
    const float* value_emb = (const float*)d_in[2];
    const int*   key_seq   = (const int*)d_in[3];
    const int*   value_seq = (const int*)d_in[4];
    const int*   mask      = (const int*)d_in[5];

    char* ws = (char*)d_ws;
    float4* KgT       = (float4*)ws;                         // 1 MB
    float*  part_hist = (float*)(ws + (1u << 20));           // 8 MB
    float*  sum_ws    = (float*)(ws + (9u << 20));           // 4 KB
    int*    c_ws      = (int*)  (ws + (9u << 20) + 4096);    // 32 B

    kvmn_gather <<<BB * KK * E4 / 256, 256, 0, stream>>>(key_emb, key_seq, KgT, sum_ws, c_ws);
    kvmn_attn   <<<NBH, 256, 0, stream>>>(hidden, KgT, value_seq, mask, part_hist, c_ws);
    kvmn_hreduce<<<64, 256, 0, stream>>>(part_hist, value_emb, sum_ws);
    kvmn_div    <<<BB, 128, 0, stream>>>(sum_ws, c_ws, (float*)d_out);
    (void)in_sizes; (void)n_in; (void)out_size; (void)ws_size;
}